// Round 7
// baseline (53.135 us; speedup 1.0000x reference)
//
#include <hip/hip_runtime.h>
#include <hip/hip_bf16.h>

#define K_Q   131072
#define B_N   1024
#define D_DIM 128
#define NCLS  10
#define NC2   20
#define NEG_INF_F (-1e9f)

#define KC    256        // floats per k-chunk
#define RST   260        // LDS row stride in floats (1040 B)
#define CB    64         // chunk-blocks per (dtile, queue)
#define NITER 8          // (K_Q/KC)/CB
#define DEPTH 3          // LDS pipeline buffers

typedef __attribute__((ext_vector_type(8))) short short8v;  // 8 bf16
typedef __attribute__((ext_vector_type(4))) float vf4;

__device__ __forceinline__ short f2bf(float f) {
    __hip_bfloat16 h = __float2bfloat16(f);
    return *reinterpret_cast<short*>(&h);
}

// async global->LDS, 16 B per lane; g is PER-LANE addr, l is wave-uniform base
__device__ __forceinline__ void gload_lds16(const float* g, float* l) {
    __builtin_amdgcn_global_load_lds(
        (const __attribute__((address_space(1))) unsigned int*)g,
        (__attribute__((address_space(3))) unsigned int*)l,
        16, 0, 0);
}

// ---------------- kernel 0: zero the atomic counters ----------------
__global__ void k_init(int* cnt, int* accCnt) {
    int t = threadIdx.x;
    if (t < NC2) cnt[t] = 0;
    if (t == 0) *accCnt = 0;
}

// ---------------- kernel 1: per-k class code + class counts ----------------
__global__ void k_code(const int* __restrict__ qp, const int* __restrict__ ql,
                       unsigned char* __restrict__ code, int* __restrict__ cnt) {
    __shared__ int lc[NC2];
    int t = threadIdx.x;
    if (t < NC2) lc[t] = 0;
    __syncthreads();
    int idx = blockIdx.x * blockDim.x + t;
    int stride = gridDim.x * blockDim.x;
    for (int k = idx; k < K_Q; k += stride) {
        int p = qp[k];
        int cd = (p == ql[k]) ? p : (p + NCLS);
        code[k] = (unsigned char)cd;
        atomicAdd(&lc[cd], 1);
    }
    __syncthreads();
    if (t < NC2) atomicAdd(&cnt[t], lc[t]);
}

// ------- kernel 2: coalesced LDS-staged one-hot MFMA, counted-vmcnt pipeline --
// Block = (cb, dtile, queue). 8 waves, 3 LDS buffers, loads never drained to 0
// inside the loop. Collective completion: each wave waits vmcnt(2) (its OWN
// slot-it loads done), then s_barrier => all waves' slot-it loads done.
__global__ __launch_bounds__(512, 6)
void k_mfma(const float* __restrict__ posq, const float* __restrict__ negq,
            const unsigned char* __restrict__ code, float* __restrict__ partial) {
    __shared__ __align__(16) float lds[DEPTH][16 * RST];   // 3 x 16.6 KB
    const int t    = threadIdx.x;
    const int wave = t >> 6;
    const int lane = t & 63;
    const int cl   = lane & 15;   // A row class / B col d / C col
    const int g    = lane >> 4;   // k-group
    const int cb   = blockIdx.x;
    const int dt   = blockIdx.y;
    const int q    = blockIdx.z;
    const float* queue = q ? negq : posq;
    const unsigned tgt = (unsigned)(cl + q * NCLS);   // code byte this row matches

    const size_t rowg = (size_t)(dt * 16 + 2 * wave) * K_Q;  // my 2 staging rows

    // preload ALL code words for my k-steps (8 independent 8-B loads)
    uint2 cw[NITER];
#pragma unroll
    for (int it = 0; it < NITER; ++it)
        cw[it] = *(const uint2*)(code + (it * CB + cb) * KC + wave * 32 + g * 8);

    // prologue: stage slots 0 and 1
#pragma unroll
    for (int it = 0; it < 2; ++it) {
        const float* g0 = queue + rowg + (size_t)(it * CB + cb) * KC;
        gload_lds16(g0 + lane * 4,       &lds[it][(2 * wave) * RST]);
        gload_lds16(g0 + K_Q + lane * 4, &lds[it][(2 * wave + 1) * RST]);
    }

    vf4 acc = (vf4){0.f, 0.f, 0.f, 0.f};

#pragma unroll
    for (int it = 0; it < NITER; ++it) {
        const int sl = it % DEPTH;

        // my slot-it loads (oldest 2) have landed when outstanding <= 2*2
        asm volatile("s_waitcnt vmcnt(4)" ::: "memory");
        asm volatile("s_barrier" ::: "memory");   // => everyone's slot-it landed

        // one-hot A from preloaded codes
        short8v a;
#pragma unroll
        for (int j = 0; j < 8; ++j) {
            unsigned b = (((j < 4) ? cw[it].x : cw[it].y) >> (8 * (j & 3))) & 0xffu;
            a[j] = (b == tgt) ? (short)0x3F80 : (short)0;
        }

        // B fragment from LDS: row cl, k-slot = wave*32 + g*8
        const float* row = &lds[sl][cl * RST + wave * 32 + g * 8];
        float4 f0 = *(const float4*)(row);
        float4 f1 = *(const float4*)(row + 4);
        short8v b;
        b[0] = f2bf(f0.x); b[1] = f2bf(f0.y); b[2] = f2bf(f0.z); b[3] = f2bf(f0.w);
        b[4] = f2bf(f1.x); b[5] = f2bf(f1.y); b[6] = f2bf(f1.z); b[7] = f2bf(f1.w);

        acc = __builtin_amdgcn_mfma_f32_16x16x32_bf16(a, b, acc, 0, 0, 0);

        asm volatile("s_barrier" ::: "memory");   // all waves done reading slot it

        if (it + 2 < NITER) {   // stage slot it+2 (overwrites slot read at it-1)
            const float* g0 = queue + rowg + (size_t)((it + 2) * CB + cb) * KC;
            gload_lds16(g0 + lane * 4,       &lds[(it + 2) % DEPTH][(2 * wave) * RST]);
            gload_lds16(g0 + K_Q + lane * 4, &lds[(it + 2) % DEPTH][(2 * wave + 1) * RST]);
        }
    }

    // epilogue: drain, then block-reduce 8 waves' acc tiles
    asm volatile("s_waitcnt vmcnt(0)" ::: "memory");
    __syncthreads();
    float* red = &lds[0][0];
    *(vf4*)&red[(wave * 64 + lane) * 4] = acc;
    __syncthreads();
    if (wave == 0) {
        vf4 s = (vf4){0.f, 0.f, 0.f, 0.f};
#pragma unroll
        for (int w = 0; w < 8; ++w) {
            vf4 v = *(vf4*)&red[(w * 64 + lane) * 4];
            s[0] += v[0]; s[1] += v[1]; s[2] += v[2]; s[3] += v[3];
        }
        const int blk = (q * 8 + dt) * CB + cb;
#pragma unroll
        for (int j = 0; j < 4; ++j) {
            int cls = g * 4 + j;   // C/D row
            if (cls < NCLS)
                partial[(size_t)blk * (NCLS * 16) + cls * 16 + cl] = s[j];
        }
    }
}

// ---------------- kernel 3: sum partials -> S[20][128] ----------------
__global__ void k_fin(const float* __restrict__ partial, float* __restrict__ S) {
    int idx = blockIdx.x * blockDim.x + threadIdx.x;  // 0..2559
    if (idx >= NC2 * D_DIM) return;
    int j = idx / D_DIM, d = idx % D_DIM;
    int q = j / NCLS, cls = j % NCLS, dt = d / 16, c16 = d & 15;
    const float* p = partial + (size_t)((q * 8 + dt) * CB) * (NCLS * 16) + cls * 16 + c16;
    float s = 0.0f;
#pragma unroll 8
    for (int cb = 0; cb < CB; ++cb) s += p[(size_t)cb * (NCLS * 16)];
    S[idx] = s;   // S[j][d]: j<10 pos class j, j>=10 neg class j-10
}

// ---------------- kernel 4: per-sample loss ----------------
__global__ void k_loss(const float* __restrict__ q, const int* __restrict__ preds,
                       const float* __restrict__ S, const int* __restrict__ cnt,
                       float* __restrict__ out, int* __restrict__ accCnt) {
    const int b = blockIdx.x;
    const int t = threadIdx.x;  // 128 threads
    const int c = preds[b];

    float qv = q[(size_t)b * D_DIM + t];
    float sp = S[c * D_DIM + t];
    float sn = S[(NCLS + c) * D_DIM + t];
    float s0 = qv * qv, s1 = qv * sp, s2 = qv * sn;

#pragma unroll
    for (int off = 32; off; off >>= 1) {
        s0 += __shfl_xor(s0, off);
        s1 += __shfl_xor(s1, off);
        s2 += __shfl_xor(s2, off);
    }
    __shared__ float red[2][3];
    int wave = t >> 6;
    if ((t & 63) == 0) { red[wave][0] = s0; red[wave][1] = s1; red[wave][2] = s2; }
    __syncthreads();
    if (t == 0) {
        float nq  = red[0][0] + red[1][0];
        float dp  = red[0][1] + red[1][1];
        float dn  = red[0][2] + red[1][2];
        float inv = 1.0f / fmaxf(sqrtf(nq), 1e-12f);
        int cp = cnt[c], cn = cnt[NCLS + c];
        float pl = (cp > 0) ? (dp * inv) / (float)(cp > 1 ? cp : 1) : NEG_INF_F;
        float nl = (cn > 0) ? (dn * inv) / (float)(cn > 1 ? cn : 1) : NEG_INF_F;
        float a  = pl / 0.07f;
        float bb = nl / 0.07f;
        float m  = fmaxf(a, bb);
        float loss = m + logf(expf(a - m) + expf(bb - m)) - a;
        out[b] = loss;
        if (a >= bb) atomicAdd(accCnt, 1);  // argmax ties -> index 0
    }
}

// ---------------- kernel 5: accuracy scalar ----------------
__global__ void k_acc(const int* __restrict__ accCnt, float* __restrict__ out) {
    out[B_N] = (float)(*accCnt) * (1.0f / (float)B_N);
}

extern "C" void kernel_launch(void* const* d_in, const int* in_sizes, int n_in,
                              void* d_out, int out_size, void* d_ws, size_t ws_size,
                              hipStream_t stream) {
    const float* q      = (const float*)d_in[0];
    // d_in[1] = k (unused downstream), d_in[2] = labels (unused)
    const int* preds    = (const int*)d_in[3];
    const float* posq   = (const float*)d_in[4];
    const float* negq   = (const float*)d_in[5];
    const int* qlabels  = (const int*)d_in[6];
    const int* qpreds   = (const int*)d_in[7];
    float* out = (float*)d_out;

    char* ws = (char*)d_ws;
    unsigned char* code = (unsigned char*)ws;           // 131072 B
    int* cnt            = (int*)(ws + 131072);          // 20 ints
    int* accCnt         = (int*)(ws + 131072 + 80);     // 1 int
    float* partial      = (float*)(ws + 131328);        // 1024 blk * 160 f32 = 655 KB
    float* S            = (float*)(ws + 131328 + 1024 * NCLS * 16 * 4);

    k_init<<<1, 64, 0, stream>>>(cnt, accCnt);
    k_code<<<256, 256, 0, stream>>>(qpreds, qlabels, code, cnt);
    k_mfma<<<dim3(CB, 8, 2), 512, 0, stream>>>(posq, negq, code, partial);
    k_fin<<<(NC2 * D_DIM + 255) / 256, 256, 0, stream>>>(partial, S);
    k_loss<<<B_N, 128, 0, stream>>>(q, preds, S, cnt, out, accCnt);
    k_acc<<<1, 1, 0, stream>>>(accCnt, out);
}